// Round 16
// baseline (216813.696 us; speedup 1.0000x reference)
//
#include <hip/hip_runtime.h>
#include <cmath>

// Problem dims (fixed): T=4096, I=512, H=2048, F=256
#define NSTEP 8191   // 4096 enc + 4095 dec
#define POLL_MAX 32768
#define RESC_MAX 8192
#define ARR_SPIN (1 << 14)

typedef unsigned long long u64;

// ---------------- marker + tagged-payload dataflow ----------------------------
// pub layout (u64):
//   hPlane:   pub[   0 + i*256 + idx]  i=0..7   (h col 8*idx+i, tag|data)
//   rhdPlane: pub[2048 + i*256 + idx]
//   hpPlane:  pub[4096 + i*256 + idx]  (only step 4095 -> mid-MLP)
//   feat:     pub[6144 + idx]
//   mark:     pub[6400 + w]            (per-WG marker, tag only)
// Protocol: payload exch (tagged, CP) -> raw s_barrier (issue-order only)
// -> marker exch. Consumer: poll ONE marker word (load + every-8th RMW rescue),
// then ACQUIRE-AGENT FENCE (buffer_inv: discard stale L1/L2 copies) and read
// payloads with plain coalesced agent loads; tag-verify + bounded RMW rescue
// remains the correctness net for any in-flight/stale window.
__device__ __forceinline__ unsigned tagOf(u64 v){ return (unsigned)(v >> 32); }
__device__ __forceinline__ void pubTag(u64* p, unsigned e, float x){
  atomicExch(p, ((u64)e << 32) | (u64)(unsigned)__float_as_int(x));
}
__device__ __forceinline__ void pubMark(u64* p, unsigned e){
  atomicExch(p, ((u64)e << 32));
}
__device__ __forceinline__ float lo32f(u64 v){ return __int_as_float((int)(unsigned)v); }

__device__ __forceinline__ int pollMark(u64* p, unsigned e){
  int spin = 0;
  for(;;){
    u64 v = ((spin & 7) == 7) ? atomicOr(p, 0ull)
          : __hip_atomic_load(p, __ATOMIC_RELAXED, __HIP_MEMORY_SCOPE_AGENT);
    if (tagOf(v) >= e) return 1;
    if (++spin >= POLL_MAX) return 0;
    __builtin_amdgcn_s_sleep(1);
  }
}
// acquire-fence (inv) then one coalesced load round; tag-verify; RMW rescue
__device__ __forceinline__ int loadPay8(u64* base, int idx, unsigned e, u64 out[8]){
  __builtin_amdgcn_fence(__ATOMIC_ACQUIRE, "agent");   // buffer_inv: fresh loads
  #pragma unroll
  for (int i = 0; i < 8; ++i)
    out[i] = __hip_atomic_load(base + i*256 + idx, __ATOMIC_RELAXED,
                               __HIP_MEMORY_SCOPE_AGENT);
  unsigned mn = 0xFFFFFFFFu;
  #pragma unroll
  for (int i = 0; i < 8; ++i){ unsigned tg = tagOf(out[i]); mn = tg < mn ? tg : mn; }
  if (mn >= e) return 1;
  int spin = 0;
  for(;;){
    #pragma unroll
    for (int i = 0; i < 8; ++i)
      if (tagOf(out[i]) < e) out[i] = atomicOr(base + i*256 + idx, 0ull);
    mn = 0xFFFFFFFFu;
    #pragma unroll
    for (int i = 0; i < 8; ++i){ unsigned tg = tagOf(out[i]); mn = tg < mn ? tg : mn; }
    if (mn >= e) return 1;
    if (++spin >= RESC_MAX) return 0;
    __builtin_amdgcn_s_sleep(1);
  }
}
__device__ __forceinline__ int poll1p(u64* p, unsigned e, u64* out){
  int spin = 0;
  for(;;){
    u64 v = ((spin & 7) == 7) ? atomicOr(p, 0ull)
          : __hip_atomic_load(p, __ATOMIC_RELAXED, __HIP_MEMORY_SCOPE_AGENT);
    if (tagOf(v) >= e){ *out = v; return 1; }
    if (++spin >= POLL_MAX) return 0;
    __builtin_amdgcn_s_sleep(1);
  }
}

// ---------------- small kernels ----------------
__global__ void fillK(float* p, int n, float v){
  for (int i = blockIdx.x*blockDim.x + threadIdx.x; i < n; i += gridDim.x*blockDim.x) p[i] = v;
}

// per-call init: h0 published as tag 0, everything else tag 0; ctrl zeroed.
__global__ void initK(u64* pub, int* ctrl, const float* __restrict__ h0){
  int t = threadIdx.x;   // 1 block x 256
  #pragma unroll
  for (int i = 0; i < 8; ++i)
    pub[i*256 + t] = (u64)(unsigned)__float_as_int(h0[8*t + i]);  // tag 0 | h0
  for (int j = 2048 + t; j < 6656; j += 256) pub[j] = 0;
  for (int i = t; i < 1024; i += 256) ctrl[i] = 0;
}

// coalesced 2-pass mean
__global__ void mean1K(const float* __restrict__ seq, const float* __restrict__ mask,
                       float* __restrict__ Sp, float* __restrict__ Cp){
  int bb = blockIdx.x, i = threadIdx.x;      // 64 blocks x 512 threads
  float s = 0.f, c = 0.f;
  for (int tt = 64*bb; tt < 64*bb + 64; ++tt){
    size_t o = (size_t)tt*512 + i;
    s += seq[o];
    c += (mask[o] != 0.f) ? 1.f : 0.f;
  }
  Sp[bb*512 + i] = s; Cp[bb*512 + i] = c;
}
__global__ void mean2K(const float* __restrict__ Sp, const float* __restrict__ Cp,
                       float* __restrict__ meanv){
  int i = threadIdx.x;                        // 1 block x 512
  float s = 0.f, c = 0.f;
  for (int bb = 0; bb < 64; ++bb){ s += Sp[bb*512 + i]; c += Cp[bb*512 + i]; }
  meanv[i] = s / (1e-6f + c);
}

// ---------------- parallel affine scan for prex/xh recurrence ----------------
__device__ __forceinline__ void scan_ac(const float* __restrict__ Gx,
                                        const float* __restrict__ mask,
                                        const float* __restrict__ seq,
                                        float mn, int r, int i, float& a, float& c){
  int src = (r < 4096) ? r : (8190 - r);
  size_t o = (size_t)src*512 + i;
  float g = Gx[o], m = mask[o], x = seq[o];
  a = (1.f - m)*g;
  c = m*x + (1.f - m)*(1.f - g)*mn;
}
__global__ void scanSegK(const float* __restrict__ Gx, const float* __restrict__ mask,
                         const float* __restrict__ seq, const float* __restrict__ meanv,
                         float* __restrict__ segA, float* __restrict__ segC){
  int bb = blockIdx.x, i = threadIdx.x;       // 64 blocks x 512 threads
  float mn = meanv[i];
  float A = 1.f, C = 0.f;
  int r1 = 128*bb + 128; if (r1 > NSTEP) r1 = NSTEP;
  for (int r = 128*bb; r < r1; ++r){
    float a, c; scan_ac(Gx, mask, seq, mn, r, i, a, c);
    A = a*A; C = a*C + c;
  }
  segA[bb*512 + i] = A; segC[bb*512 + i] = C;
}
__global__ void scanFixK(const float* __restrict__ segA, const float* __restrict__ segC,
                         const float* __restrict__ prex0, float* __restrict__ segX0){
  int i = threadIdx.x;                        // 1 block x 512
  float x = prex0[i];
  for (int bb = 0; bb < 64; ++bb){
    segX0[bb*512 + i] = x;
    x = segA[bb*512 + i]*x + segC[bb*512 + i];
  }
}
__global__ void scanEmitK(const float* __restrict__ Gx, const float* __restrict__ mask,
                          const float* __restrict__ seq, const float* __restrict__ meanv,
                          const float* __restrict__ segX0, float* __restrict__ xh){
  int bb = blockIdx.x, i = threadIdx.x;
  float mn = meanv[i];
  float x = segX0[bb*512 + i];
  int r1 = 128*bb + 128; if (r1 > NSTEP) r1 = NSTEP;
  for (int r = 128*bb; r < r1; ++r){
    float a, c; scan_ac(Gx, mask, seq, mn, r, i, a, c);
    x = a*x + c;
    xh[(size_t)r*512 + i] = x;
  }
}

// ---------------- generic fp32 GEMM: C = act(A@B + bias) [+ C if beta] ----------
#define BM 128
#define BN 128
#define BK 8
__launch_bounds__(256)
__global__ void gemmK(const float* __restrict__ A, const float* __restrict__ B,
                      float* __restrict__ C, int M, int N, int K,
                      const float* __restrict__ bias, int act, int beta, int amap,
                      int rowoff){
  __shared__ float As[BK][BM+4];
  __shared__ float Bs[BK][BN+4];
  int tid = threadIdx.x;
  int r0 = blockIdx.y * BM, c0 = blockIdx.x * BN;
  int tr = tid >> 4, tc = tid & 15;
  int ar = tid >> 1, ak = (tid & 1)*4;
  int bkr = tid >> 5, bkc = (tid & 31)*4;
  float acc[8][8] = {};

  for (int k0 = 0; k0 < K; k0 += BK){
    int r = r0 + ar;
    float4 av = make_float4(0.f,0.f,0.f,0.f);
    if (r < M){
      int g = rowoff + r;
      int rs = amap ? (g < 4096 ? g : 8190 - g) : r;
      av = *(const float4*)(A + (size_t)rs*K + k0 + ak);
    }
    As[ak+0][ar] = av.x; As[ak+1][ar] = av.y; As[ak+2][ar] = av.z; As[ak+3][ar] = av.w;
    *(float4*)(&Bs[bkr][bkc]) = *(const float4*)(B + (size_t)(k0 + bkr)*N + c0 + bkc);
    __syncthreads();
    #pragma unroll
    for (int kk = 0; kk < BK; ++kk){
      float a[8], bb[8];
      #pragma unroll
      for (int i = 0; i < 8; ++i) a[i]  = As[kk][tr*8 + i];
      #pragma unroll
      for (int j = 0; j < 8; ++j) bb[j] = Bs[kk][tc*8 + j];
      #pragma unroll
      for (int i = 0; i < 8; ++i)
        #pragma unroll
        for (int j = 0; j < 8; ++j)
          acc[i][j] += a[i]*bb[j];
    }
    __syncthreads();
  }

  #pragma unroll
  for (int i = 0; i < 8; ++i){
    int r = r0 + tr*8 + i;
    if (r >= M) continue;
    float v[8];
    #pragma unroll
    for (int j = 0; j < 8; ++j){
      int c = c0 + tc*8 + j;
      float x = acc[i][j];
      if (bias) x += bias[c];
      if (act == 1) x = expf(-fmaxf(x, 0.f));
      v[j] = x;
    }
    float* cp = C + (size_t)r*N + c0 + tc*8;
    if (beta){
      float4 o0 = *(const float4*)(cp);
      float4 o1 = *(const float4*)(cp + 4);
      v[0]+=o0.x; v[1]+=o0.y; v[2]+=o0.z; v[3]+=o0.w;
      v[4]+=o1.x; v[5]+=o1.y; v[6]+=o1.z; v[7]+=o1.w;
    }
    *(float4*)(cp)     = make_float4(v[0],v[1],v[2],v[3]);
    *(float4*)(cp + 4) = make_float4(v[4],v[5],v[6],v[7]);
  }
}

// ---------------- persistent chunk kernel (marker dataflow) --------------------
// 256 WGs x 256 thr, 1 WG/CU. WG w owns output cols [8w,8w+8); thread t owns
// k-slice [8t,8t+8) and consumes WG t's line. U register-resident.
// Overwrite safety: distance-2 dependency (h(e+2) publish requires rhd(e+1)
// from all, which requires every consumer read h(e)). Tags strictly increase.
__launch_bounds__(256, 1)
__global__ void rnnPersK(const float* __restrict__ U, const float* __restrict__ PreC,
                         int c0, int len, int ev0,
                         const float* __restrict__ Gh, const float* __restrict__ dts,
                         const float* __restrict__ We, const float* __restrict__ be,
                         const float* __restrict__ Wd, const float* __restrict__ bd,
                         u64* pub, float* __restrict__ HpDec, int* arrival){
  const int w = blockIdx.x;
  const int t = threadIdx.x;
  const int lane = t & 63, wv = t >> 6;
  __shared__ float redA[4][8], redB[4][8], redH[4][8], ldsH[8], ldsHd[8];
  __shared__ int okArr;

  u64* hP   = pub;
  u64* rhdP = pub + 2048;
  u64* hpP  = pub + 4096;
  u64* feat = pub + 6144;
  u64* mark = pub + 6400;

  // residency check: all 256 WGs must arrive, else everyone bails fast.
  if (t == 0){
    atomicAdd(arrival, 1);
    int ok = 1, spin = 0;
    while (atomicOr(arrival, 0) < 256){
      if (++spin >= ARR_SPIN){ ok = 0; break; }
      __builtin_amdgcn_s_sleep(2);
    }
    okArr = ok;
  }
  __syncthreads();
  if (!okArr){ if (t == 0) HpDec[w] = 77777.f; return; }

  // register-resident U slices: uz/ur/uh[cc][i] = U[8t+i][{0,2048,4096}+8w+cc]
  float uz[8][8], ur[8][8], uh[8][8];
  #pragma unroll
  for (int i = 0; i < 8; ++i){
    const float* row = U + (size_t)(8*t + i)*6144 + 8*w;
    #pragma unroll
    for (int cc = 0; cc < 8; ++cc){
      uz[cc][i] = row[cc];
      ur[cc][i] = row[2048 + cc];
      uh[cc][i] = row[4096 + cc];
    }
  }

  unsigned e = (unsigned)ev0;

  // one-step-ahead prefetch of precomputed tables (plain loads)
  float ghn[8]; float pzn = 0.f, prn = 0.f, phn = 0.f, dtn = 0.f;
  auto prefetch = [&](int g){
    int src = (g < 4096) ? g : (8190 - g);
    const float* gr = Gh + (size_t)src*2048 + 8*t;
    #pragma unroll
    for (int i = 0; i < 8; ++i) ghn[i] = gr[i];
    const float* prow = PreC + (size_t)(g - c0)*6144;
    if (t < 8){ pzn = prow[8*w + t]; phn = prow[4096 + 8*w + t]; dtn = dts[src]; }
    else if (t < 16){ prn = prow[2048 + 8*w + (t - 8)]; }
  };
  prefetch(c0);

  for (int sl = 0; sl < len; ++sl){
    int g = c0 + sl;

    if (g == 4096){
      // ---- mid MLP: h = relu(relu(hp)@We + be) @ Wd + bd ----
      {
        int okM = pollMark(mark + t, e);
        u64 hpw[8];
        int okP = okM ? loadPay8(hpP, t, e, hpw) : 0;
        if (__syncthreads_or(!okP)) goto bail;
        float part = 0.f;
        #pragma unroll
        for (int i = 0; i < 8; ++i)
          part += fmaxf(lo32f(hpw[i]), 0.f) * We[(size_t)(8*t + i)*256 + w];
        #pragma unroll
        for (int o = 32; o; o >>= 1) part += __shfl_down(part, o);
        if (lane == 0) redA[wv][0] = part;
        __syncthreads();
        if (t == 0)
          pubTag(feat + w, e + 1,
                 fmaxf(redA[0][0]+redA[1][0]+redA[2][0]+redA[3][0] + be[w], 0.f));
      }
      {
        u64 fw;
        int okF = poll1p(feat + t, e + 1, &fw);      // single tagged word
        if (__syncthreads_or(!okF)) goto bail;
        float fv = lo32f(fw);
        #pragma unroll
        for (int cc = 0; cc < 8; ++cc){
          float v2 = fv * Wd[(size_t)t*2048 + 8*w + cc];
          #pragma unroll
          for (int o = 32; o; o >>= 1) v2 += __shfl_down(v2, o);
          if (lane == 0) redB[wv][cc] = v2;
        }
        __syncthreads();
        if (t < 8)
          pubTag(hP + t*256 + w, e + 2,
                 redB[0][t]+redB[1][t]+redB[2][t]+redB[3][t] + bd[8*w + t]);
        __syncthreads();                             // full drain (rare path)
        if (t == 0) pubMark(mark + w, e + 2);
      }
      e += 2;
    }

    {
      float ghc[8];
      #pragma unroll
      for (int i = 0; i < 8; ++i) ghc[i] = ghn[i];
      float pz = pzn, pr = prn, ph = phn, dtv = dtn;

      // ---------- phase A: z,r = sigmoid(pre + (gh*h)@U1) ----------
      int okA = pollMark(mark + t, e);               // one marker word per thread
      u64 hw[8];
      int okP = okA ? loadPay8(hP, t, e, hw) : 0;    // fence+coalesced loads
      float hv[8], hd[8];
      #pragma unroll
      for (int i = 0; i < 8; ++i){
        hv[i] = lo32f(hw[i]);
        hd[i] = hv[i] * ghc[i];
      }
      if (t == w){
        #pragma unroll
        for (int i = 0; i < 8; ++i){ ldsH[i] = hv[i]; ldsHd[i] = hd[i]; }
      }
      if (__syncthreads_or(!okP)) goto bail;
      if (sl + 1 < len) prefetch(g + 1);

      float accz[8], accr[8];
      #pragma unroll
      for (int cc = 0; cc < 8; ++cc){
        float az = 0.f, ar_ = 0.f;
        #pragma unroll
        for (int i = 0; i < 8; ++i){ az += hd[i]*uz[cc][i]; ar_ += hd[i]*ur[cc][i]; }
        accz[cc] = az; accr[cc] = ar_;
      }
      #pragma unroll
      for (int cc = 0; cc < 8; ++cc){
        float v = accz[cc];
        #pragma unroll
        for (int o = 32; o; o >>= 1) v += __shfl_down(v, o);
        if (lane == 0) redA[wv][cc] = v;
        v = accr[cc];
        #pragma unroll
        for (int o = 32; o; o >>= 1) v += __shfl_down(v, o);
        if (lane == 0) redB[wv][cc] = v;
      }
      __syncthreads();
      float zreg = 0.f;
      if (t < 8){
        float s = redA[0][t]+redA[1][t]+redA[2][t]+redA[3][t] + pz;
        zreg = 1.f/(1.f + expf(-s));                 // register, used in phase B
      } else if (t < 16){
        int cc = t - 8;
        float s = redB[0][cc]+redB[1][cc]+redB[2][cc]+redB[3][cc] + pr;
        float r = 1.f/(1.f + expf(-s));
        pubTag(rhdP + cc*256 + w, e + 1, r * ldsHd[cc]);  // rhd payload
      }
      // issue-order barrier only (no vmcnt drain): rescue covers in-flight exchs
      asm volatile("" ::: "memory");
      __builtin_amdgcn_s_barrier();
      asm volatile("" ::: "memory");
      if (t == 0) pubMark(mark + w, e + 1);          // marker: rhd(e+1) issued

      // ---------- phase B: htil = tanh(pre_h + (r*hd)@U2); h update ----------
      int okB = pollMark(mark + t, e + 1);
      u64 rw[8];
      int okQ = okB ? loadPay8(rhdP, t, e + 1, rw) : 0;
      if (__syncthreads_or(!okQ)) goto bail;
      float rv[8];
      #pragma unroll
      for (int i = 0; i < 8; ++i) rv[i] = lo32f(rw[i]);

      float acch[8];
      #pragma unroll
      for (int cc = 0; cc < 8; ++cc){
        float a = 0.f;
        #pragma unroll
        for (int i = 0; i < 8; ++i) a += rv[i]*uh[cc][i];
        acch[cc] = a;
      }
      #pragma unroll
      for (int cc = 0; cc < 8; ++cc){
        float v = acch[cc];
        #pragma unroll
        for (int o = 32; o; o >>= 1) v += __shfl_down(v, o);
        if (lane == 0) redH[wv][cc] = v;
      }
      __syncthreads();
      if (t < 8){
        float u2   = redH[0][t]+redH[1][t]+redH[2][t]+redH[3][t] + ph;
        float htil = tanhf(u2);
        float z = zreg, hdv = ldsHd[t], hold = ldsH[t];
        float hp = z*hdv + (1.f - z)*htil;
        float dh = (1.f - z)*(htil - hdv);
        pubTag(hP + t*256 + w, e + 2, hold + dtv*dh);      // h payload
        if (g == 4095) pubTag(hpP + t*256 + w, e + 2, hp); // hp for the mid-MLP
        if (g >= 4096) HpDec[(size_t)(8190 - g)*2048 + 8*w + t] = hp; // pre-reversed
      }
      // issue-order barrier only (no vmcnt drain)
      asm volatile("" ::: "memory");
      __builtin_amdgcn_s_barrier();
      asm volatile("" ::: "memory");
      if (t == 0) pubMark(mark + w, e + 2);          // marker: h(e+2) issued
      e += 2;
    }
  }
  return;

bail:
  if (t == 0) HpDec[w] = 77777.f;    // loud, diagnosable failure signature
}

// ---------------- launch ----------------
extern "C" void kernel_launch(void* const* d_in, const int* in_sizes, int n_in,
                              void* d_out, int out_size, void* d_ws, size_t ws_size,
                              hipStream_t stream){
  (void)in_sizes; (void)n_in;
  const float* seq   = (const float*)d_in[0];
  const float* mask  = (const float*)d_in[1];
  const float* delta = (const float*)d_in[2];
  const float* dt    = (const float*)d_in[3];
  const float* h0    = (const float*)d_in[4];
  /* d_in[5] = dh0: carried dh never read by the reference cell */
  const float* prex0 = (const float*)d_in[6];
  const float* Wgx   = (const float*)d_in[7];
  const float* bgx   = (const float*)d_in[8];
  const float* Wgh   = (const float*)d_in[9];
  const float* bgh   = (const float*)d_in[10];
  const float* W     = (const float*)d_in[11];
  const float* U     = (const float*)d_in[12];
  const float* V     = (const float*)d_in[13];
  const float* b     = (const float*)d_in[14];
  const float* We    = (const float*)d_in[15];
  const float* be    = (const float*)d_in[16];
  const float* Wd    = (const float*)d_in[17];
  const float* bd    = (const float*)d_in[18];
  const float* Wo    = (const float*)d_in[19];
  const float* bo    = (const float*)d_in[20];

  float* wsf = (float*)d_ws;
  size_t wsFloats = ws_size / 4;
  size_t off = 0;
  u64*   pub    = (u64*)(wsf + off);  off += 13312;      // 6656 u64 (planes+feat+mark)
  int*   ctrl   = (int*)(wsf + off);  off += 1024;       // arrival counters
  float* meanv  = wsf + off;  off += 512;
  float* Sp     = wsf + off;  off += (size_t)64*512;
  float* Cp     = wsf + off;  off += (size_t)64*512;
  float* Gh     = wsf + off;  off += (size_t)4096*2048;
  float* xh_all = wsf + off;  off += (size_t)NSTEP*512;
  float* HpDec  = wsf + off;  off += (size_t)4095*2048;
  size_t fixedF = off;

  // chunk area: overlays {Gx, scan temps} during precompute, PreTab chunk after
  float* area  = wsf + fixedF;
  float* Gx    = area;                                   // 4096*512
  float* segA  = area + (size_t)4096*512;                // 64*512
  float* segC  = segA + (size_t)64*512;
  float* segX0 = segC + (size_t)64*512;
  size_t preNeed = (size_t)4096*512 + (size_t)3*64*512;

  size_t areaF = (wsFloats > fixedF) ? (wsFloats - fixedF) : 0;
  long chunkSteps = (long)(areaF / 6144);
  if (areaF < preNeed || chunkSteps < 64){
    fillK<<<dim3(256), dim3(256), 0, stream>>>((float*)d_out, out_size,
                                               1.0e6f + (float)(ws_size >> 20));
    return;
  }
  if (chunkSteps > NSTEP) chunkSteps = NSTEP;
  int nch  = (int)((NSTEP + chunkSteps - 1) / chunkSteps);
  if (nch > 128) nch = 128;                        // ctrl capacity guard
  int clen = (NSTEP + nch - 1) / nch;

  // ---- precompute ----
  mean1K<<<dim3(64), dim3(512), 0, stream>>>(seq, mask, Sp, Cp);
  mean2K<<<dim3(1),  dim3(512), 0, stream>>>(Sp, Cp, meanv);
  gemmK<<<dim3(4, 32),  dim3(256), 0, stream>>>(delta, Wgx, Gx, 4096, 512, 512, bgx, 1, 0, 0, 0);
  gemmK<<<dim3(16, 32), dim3(256), 0, stream>>>(delta, Wgh, Gh, 4096, 2048, 512, bgh, 1, 0, 0, 0);
  scanSegK<<<dim3(64), dim3(512), 0, stream>>>(Gx, mask, seq, meanv, segA, segC);
  scanFixK<<<dim3(1),  dim3(512), 0, stream>>>(segA, segC, prex0, segX0);
  scanEmitK<<<dim3(64), dim3(512), 0, stream>>>(Gx, mask, seq, meanv, segX0, xh_all);
  initK<<<dim3(1), dim3(256), 0, stream>>>(pub, ctrl, h0);

  // ---- chunked recurrence: [PreTab GEMMs] then persistent marker-dataflow ----
  int ev = 0, chunkIdx = 0;
  for (int c0 = 0; c0 < NSTEP; c0 += clen, ++chunkIdx){
    int len = (c0 + clen <= NSTEP) ? clen : (NSTEP - c0);
    int gy  = (len + 127) / 128;
    gemmK<<<dim3(48, gy), dim3(256), 0, stream>>>(xh_all + (size_t)c0*512, W, area,
                                                  len, 6144, 512, b, 0, 0, 0, 0);
    gemmK<<<dim3(48, gy), dim3(256), 0, stream>>>(mask, V, area,
                                                  len, 6144, 512, nullptr, 0, 1, 1, c0);

    rnnPersK<<<dim3(256), dim3(256), 0, stream>>>(U, area, c0, len, ev, Gh, dt,
                                                  We, be, Wd, bd,
                                                  pub, HpDec, ctrl + 4*chunkIdx);
    ev += 2*len + ((c0 <= 4096 && 4096 < c0 + len) ? 2 : 0);
  }

  // out = HpDec @ Wo + bo : 4095x512, K=2048 (HpDec stored pre-reversed)
  gemmK<<<dim3(4, 32), dim3(256), 0, stream>>>(HpDec, Wo, (float*)d_out,
                                               4095, 512, 2048, bo, 0, 0, 0, 0);
}

// Round 17
// 111026.562 us; speedup vs baseline: 1.9528x; 1.9528x over previous
//
#include <hip/hip_runtime.h>
#include <cmath>

// Problem dims (fixed): T=4096, I=512, H=2048, F=256
#define NSTEP 8191   // 4096 enc + 4095 dec
#define POLL_MAX 32768
#define RESC_MAX 8192
#define ARR_SPIN (1 << 14)

typedef unsigned long long u64;

// ---------------- marker + tagged-payload dataflow (R15-proven) ----------------
// pub layout (u64):
//   hPlane:   pub[   0 + i*256 + idx]  i=0..7   (h col 8*idx+i, tag|data)
//   rhdPlane: pub[2048 + i*256 + idx]
//   hpPlane:  pub[4096 + i*256 + idx]  (only step 4095 -> mid-MLP)
//   feat:     pub[6144 + idx]
//   mark:     pub[6400 + w]            (per-WG marker, tag only)
// Protocol: payload exch (tagged, CP) -> __syncthreads (vmcnt drain) -> marker
// exch. Consumer: poll ONE marker word (load + every-8th RMW rescue), then read
// payloads (load round, tag-verified) with bounded RMW rescue for stale words.
__device__ __forceinline__ unsigned tagOf(u64 v){ return (unsigned)(v >> 32); }
__device__ __forceinline__ void pubTag(u64* p, unsigned e, float x){
  atomicExch(p, ((u64)e << 32) | (u64)(unsigned)__float_as_int(x));
}
__device__ __forceinline__ void pubMark(u64* p, unsigned e){
  atomicExch(p, ((u64)e << 32));
}
__device__ __forceinline__ float lo32f(u64 v){ return __int_as_float((int)(unsigned)v); }

__device__ __forceinline__ int pollMark(u64* p, unsigned e){
  int spin = 0;
  for(;;){
    u64 v = ((spin & 7) == 7) ? atomicOr(p, 0ull)
          : __hip_atomic_load(p, __ATOMIC_RELAXED, __HIP_MEMORY_SCOPE_AGENT);
    if (tagOf(v) >= e) return 1;
    if (++spin >= POLL_MAX) return 0;
    __builtin_amdgcn_s_sleep(1);
  }
}
// one fast load round; tag-verify; bounded RMW rescue for stale words
__device__ __forceinline__ int loadPay8(u64* base, int idx, unsigned e, u64 out[8]){
  #pragma unroll
  for (int i = 0; i < 8; ++i)
    out[i] = __hip_atomic_load(base + i*256 + idx, __ATOMIC_RELAXED,
                               __HIP_MEMORY_SCOPE_AGENT);
  unsigned mn = 0xFFFFFFFFu;
  #pragma unroll
  for (int i = 0; i < 8; ++i){ unsigned tg = tagOf(out[i]); mn = tg < mn ? tg : mn; }
  if (mn >= e) return 1;
  int spin = 0;
  for(;;){
    #pragma unroll
    for (int i = 0; i < 8; ++i)
      if (tagOf(out[i]) < e) out[i] = atomicOr(base + i*256 + idx, 0ull);
    mn = 0xFFFFFFFFu;
    #pragma unroll
    for (int i = 0; i < 8; ++i){ unsigned tg = tagOf(out[i]); mn = tg < mn ? tg : mn; }
    if (mn >= e) return 1;
    if (++spin >= RESC_MAX) return 0;
    __builtin_amdgcn_s_sleep(1);
  }
}
__device__ __forceinline__ int poll1p(u64* p, unsigned e, u64* out){
  int spin = 0;
  for(;;){
    u64 v = ((spin & 7) == 7) ? atomicOr(p, 0ull)
          : __hip_atomic_load(p, __ATOMIC_RELAXED, __HIP_MEMORY_SCOPE_AGENT);
    if (tagOf(v) >= e){ *out = v; return 1; }
    if (++spin >= POLL_MAX) return 0;
    __builtin_amdgcn_s_sleep(1);
  }
}

// ---------------- small kernels ----------------
__global__ void fillK(float* p, int n, float v){
  for (int i = blockIdx.x*blockDim.x + threadIdx.x; i < n; i += gridDim.x*blockDim.x) p[i] = v;
}

// per-call init: h0 published as tag 0, everything else tag 0; ctrl zeroed.
__global__ void initK(u64* pub, int* ctrl, const float* __restrict__ h0){
  int t = threadIdx.x;   // 1 block x 256
  #pragma unroll
  for (int i = 0; i < 8; ++i)
    pub[i*256 + t] = (u64)(unsigned)__float_as_int(h0[8*t + i]);  // tag 0 | h0
  for (int j = 2048 + t; j < 6656; j += 256) pub[j] = 0;
  for (int i = t; i < 1024; i += 256) ctrl[i] = 0;
}

// coalesced 2-pass mean
__global__ void mean1K(const float* __restrict__ seq, const float* __restrict__ mask,
                       float* __restrict__ Sp, float* __restrict__ Cp){
  int bb = blockIdx.x, i = threadIdx.x;      // 64 blocks x 512 threads
  float s = 0.f, c = 0.f;
  for (int tt = 64*bb; tt < 64*bb + 64; ++tt){
    size_t o = (size_t)tt*512 + i;
    s += seq[o];
    c += (mask[o] != 0.f) ? 1.f : 0.f;
  }
  Sp[bb*512 + i] = s; Cp[bb*512 + i] = c;
}
__global__ void mean2K(const float* __restrict__ Sp, const float* __restrict__ Cp,
                       float* __restrict__ meanv){
  int i = threadIdx.x;                        // 1 block x 512
  float s = 0.f, c = 0.f;
  for (int bb = 0; bb < 64; ++bb){ s += Sp[bb*512 + i]; c += Cp[bb*512 + i]; }
  meanv[i] = s / (1e-6f + c);
}

// ---------------- parallel affine scan for prex/xh recurrence ----------------
__device__ __forceinline__ void scan_ac(const float* __restrict__ Gx,
                                        const float* __restrict__ mask,
                                        const float* __restrict__ seq,
                                        float mn, int r, int i, float& a, float& c){
  int src = (r < 4096) ? r : (8190 - r);
  size_t o = (size_t)src*512 + i;
  float g = Gx[o], m = mask[o], x = seq[o];
  a = (1.f - m)*g;
  c = m*x + (1.f - m)*(1.f - g)*mn;
}
__global__ void scanSegK(const float* __restrict__ Gx, const float* __restrict__ mask,
                         const float* __restrict__ seq, const float* __restrict__ meanv,
                         float* __restrict__ segA, float* __restrict__ segC){
  int bb = blockIdx.x, i = threadIdx.x;       // 64 blocks x 512 threads
  float mn = meanv[i];
  float A = 1.f, C = 0.f;
  int r1 = 128*bb + 128; if (r1 > NSTEP) r1 = NSTEP;
  for (int r = 128*bb; r < r1; ++r){
    float a, c; scan_ac(Gx, mask, seq, mn, r, i, a, c);
    A = a*A; C = a*C + c;
  }
  segA[bb*512 + i] = A; segC[bb*512 + i] = C;
}
__global__ void scanFixK(const float* __restrict__ segA, const float* __restrict__ segC,
                         const float* __restrict__ prex0, float* __restrict__ segX0){
  int i = threadIdx.x;                        // 1 block x 512
  float x = prex0[i];
  for (int bb = 0; bb < 64; ++bb){
    segX0[bb*512 + i] = x;
    x = segA[bb*512 + i]*x + segC[bb*512 + i];
  }
}
__global__ void scanEmitK(const float* __restrict__ Gx, const float* __restrict__ mask,
                          const float* __restrict__ seq, const float* __restrict__ meanv,
                          const float* __restrict__ segX0, float* __restrict__ xh){
  int bb = blockIdx.x, i = threadIdx.x;
  float mn = meanv[i];
  float x = segX0[bb*512 + i];
  int r1 = 128*bb + 128; if (r1 > NSTEP) r1 = NSTEP;
  for (int r = 128*bb; r < r1; ++r){
    float a, c; scan_ac(Gx, mask, seq, mn, r, i, a, c);
    x = a*x + c;
    xh[(size_t)r*512 + i] = x;
  }
}

// ---------------- fp32 GEMM, 2x2-quadrant register tiling --------------------
// C = act(A@B + bias) [+ C if beta]. A: M x K, B: K x N row-major.
// amap=1: A row r reads source row map(rowoff+r), map(g)=g<4096?g:8190-g.
// Thread (tr,tc) in 16x16 grid computes rows {tr*4, 64+tr*4}+0..3 and cols
// {tc*4, 64+tc*4}+0..3 -> all LDS reads are float4, conflict-free (A: 4 addrs
// 16B apart + broadcast; B: 16 addrs spanning 256B = 2-way = free).
#define BM 128
#define BN 128
#define BK 8
__launch_bounds__(256)
__global__ void gemmK(const float* __restrict__ A, const float* __restrict__ B,
                      float* __restrict__ C, int M, int N, int K,
                      const float* __restrict__ bias, int act, int beta, int amap,
                      int rowoff){
  __shared__ float As[BK][BM+4];
  __shared__ float Bs[BK][BN+4];
  int tid = threadIdx.x;
  int r0 = blockIdx.y * BM, c0 = blockIdx.x * BN;
  int tr = tid >> 4, tc = tid & 15;
  int ar = tid >> 1, ak = (tid & 1)*4;
  int bkr = tid >> 5, bkc = (tid & 31)*4;
  float acc[2][2][4][4] = {};

  for (int k0 = 0; k0 < K; k0 += BK){
    int r = r0 + ar;
    float4 av = make_float4(0.f,0.f,0.f,0.f);
    if (r < M){
      int g = rowoff + r;
      int rs = amap ? (g < 4096 ? g : 8190 - g) : r;
      av = *(const float4*)(A + (size_t)rs*K + k0 + ak);
    }
    As[ak+0][ar] = av.x; As[ak+1][ar] = av.y; As[ak+2][ar] = av.z; As[ak+3][ar] = av.w;
    *(float4*)(&Bs[bkr][bkc]) = *(const float4*)(B + (size_t)(k0 + bkr)*N + c0 + bkc);
    __syncthreads();
    #pragma unroll
    for (int kk = 0; kk < BK; ++kk){
      float4 a0 = *(const float4*)(&As[kk][tr*4]);
      float4 a1 = *(const float4*)(&As[kk][64 + tr*4]);
      float4 b0 = *(const float4*)(&Bs[kk][tc*4]);
      float4 b1 = *(const float4*)(&Bs[kk][64 + tc*4]);
      float avr[2][4] = {{a0.x,a0.y,a0.z,a0.w},{a1.x,a1.y,a1.z,a1.w}};
      float bvr[2][4] = {{b0.x,b0.y,b0.z,b0.w},{b1.x,b1.y,b1.z,b1.w}};
      #pragma unroll
      for (int ri = 0; ri < 2; ++ri)
        #pragma unroll
        for (int ci = 0; ci < 2; ++ci)
          #pragma unroll
          for (int ii = 0; ii < 4; ++ii)
            #pragma unroll
            for (int jj = 0; jj < 4; ++jj)
              acc[ri][ci][ii][jj] += avr[ri][ii]*bvr[ci][jj];
    }
    __syncthreads();
  }

  #pragma unroll
  for (int ri = 0; ri < 2; ++ri)
    #pragma unroll
    for (int ii = 0; ii < 4; ++ii){
      int r = r0 + ri*64 + tr*4 + ii;
      if (r >= M) continue;
      #pragma unroll
      for (int ci = 0; ci < 2; ++ci){
        int cbase = c0 + ci*64 + tc*4;
        float v[4];
        #pragma unroll
        for (int jj = 0; jj < 4; ++jj){
          float x = acc[ri][ci][ii][jj];
          if (bias) x += bias[cbase + jj];
          if (act == 1) x = expf(-fmaxf(x, 0.f));
          v[jj] = x;
        }
        float* cp = C + (size_t)r*N + cbase;
        if (beta){
          float4 o = *(const float4*)cp;
          v[0]+=o.x; v[1]+=o.y; v[2]+=o.z; v[3]+=o.w;
        }
        *(float4*)cp = make_float4(v[0],v[1],v[2],v[3]);
      }
    }
}

// ---------------- persistent chunk kernel (marker dataflow, exact R15) ---------
// 256 WGs x 256 thr, 1 WG/CU. WG w owns output cols [8w,8w+8); thread t owns
// k-slice [8t,8t+8) and consumes WG t's line. U register-resident.
__launch_bounds__(256, 1)
__global__ void rnnPersK(const float* __restrict__ U, const float* __restrict__ PreC,
                         int c0, int len, int ev0,
                         const float* __restrict__ Gh, const float* __restrict__ dts,
                         const float* __restrict__ We, const float* __restrict__ be,
                         const float* __restrict__ Wd, const float* __restrict__ bd,
                         u64* pub, float* __restrict__ HpDec, int* arrival){
  const int w = blockIdx.x;
  const int t = threadIdx.x;
  const int lane = t & 63, wv = t >> 6;
  __shared__ float redA[4][8], redB[4][8], redH[4][8], ldsH[8], ldsHd[8];
  __shared__ int okArr;

  u64* hP   = pub;
  u64* rhdP = pub + 2048;
  u64* hpP  = pub + 4096;
  u64* feat = pub + 6144;
  u64* mark = pub + 6400;

  // residency check: all 256 WGs must arrive, else everyone bails fast.
  if (t == 0){
    atomicAdd(arrival, 1);
    int ok = 1, spin = 0;
    while (atomicOr(arrival, 0) < 256){
      if (++spin >= ARR_SPIN){ ok = 0; break; }
      __builtin_amdgcn_s_sleep(2);
    }
    okArr = ok;
  }
  __syncthreads();
  if (!okArr){ if (t == 0) HpDec[w] = 77777.f; return; }

  // register-resident U slices: uz/ur/uh[cc][i] = U[8t+i][{0,2048,4096}+8w+cc]
  float uz[8][8], ur[8][8], uh[8][8];
  #pragma unroll
  for (int i = 0; i < 8; ++i){
    const float* row = U + (size_t)(8*t + i)*6144 + 8*w;
    #pragma unroll
    for (int cc = 0; cc < 8; ++cc){
      uz[cc][i] = row[cc];
      ur[cc][i] = row[2048 + cc];
      uh[cc][i] = row[4096 + cc];
    }
  }

  unsigned e = (unsigned)ev0;

  // one-step-ahead prefetch of precomputed tables (plain loads)
  float ghn[8]; float pzn = 0.f, prn = 0.f, phn = 0.f, dtn = 0.f;
  auto prefetch = [&](int g){
    int src = (g < 4096) ? g : (8190 - g);
    const float* gr = Gh + (size_t)src*2048 + 8*t;
    #pragma unroll
    for (int i = 0; i < 8; ++i) ghn[i] = gr[i];
    const float* prow = PreC + (size_t)(g - c0)*6144;
    if (t < 8){ pzn = prow[8*w + t]; phn = prow[4096 + 8*w + t]; dtn = dts[src]; }
    else if (t < 16){ prn = prow[2048 + 8*w + (t - 8)]; }
  };
  prefetch(c0);

  for (int sl = 0; sl < len; ++sl){
    int g = c0 + sl;

    if (g == 4096){
      // ---- mid MLP: h = relu(relu(hp)@We + be) @ Wd + bd ----
      {
        int okM = pollMark(mark + t, e);
        u64 hpw[8];
        int okP = okM ? loadPay8(hpP, t, e, hpw) : 0;
        if (__syncthreads_or(!okP)) goto bail;
        float part = 0.f;
        #pragma unroll
        for (int i = 0; i < 8; ++i)
          part += fmaxf(lo32f(hpw[i]), 0.f) * We[(size_t)(8*t + i)*256 + w];
        #pragma unroll
        for (int o = 32; o; o >>= 1) part += __shfl_down(part, o);
        if (lane == 0) redA[wv][0] = part;
        __syncthreads();
        if (t == 0)
          pubTag(feat + w, e + 1,
                 fmaxf(redA[0][0]+redA[1][0]+redA[2][0]+redA[3][0] + be[w], 0.f));
      }
      {
        u64 fw;
        int okF = poll1p(feat + t, e + 1, &fw);      // single tagged word
        if (__syncthreads_or(!okF)) goto bail;
        float fv = lo32f(fw);
        #pragma unroll
        for (int cc = 0; cc < 8; ++cc){
          float v2 = fv * Wd[(size_t)t*2048 + 8*w + cc];
          #pragma unroll
          for (int o = 32; o; o >>= 1) v2 += __shfl_down(v2, o);
          if (lane == 0) redB[wv][cc] = v2;
        }
        __syncthreads();
        if (t < 8)
          pubTag(hP + t*256 + w, e + 2,
                 redB[0][t]+redB[1][t]+redB[2][t]+redB[3][t] + bd[8*w + t]);
        __syncthreads();                             // drain h exchs (vmcnt)
        if (t == 0) pubMark(mark + w, e + 2);
      }
      e += 2;
    }

    {
      float ghc[8];
      #pragma unroll
      for (int i = 0; i < 8; ++i) ghc[i] = ghn[i];
      float pz = pzn, pr = prn, ph = phn, dtv = dtn;

      // ---------- phase A: z,r = sigmoid(pre + (gh*h)@U1) ----------
      int okA = pollMark(mark + t, e);               // one marker word per thread
      u64 hw[8];
      int okP = okA ? loadPay8(hP, t, e, hw) : 0;    // tag-verified payload read
      float hv[8], hd[8];
      #pragma unroll
      for (int i = 0; i < 8; ++i){
        hv[i] = lo32f(hw[i]);
        hd[i] = hv[i] * ghc[i];
      }
      if (t == w){
        #pragma unroll
        for (int i = 0; i < 8; ++i){ ldsH[i] = hv[i]; ldsHd[i] = hd[i]; }
      }
      if (__syncthreads_or(!okP)) goto bail;
      if (sl + 1 < len) prefetch(g + 1);

      float accz[8], accr[8];
      #pragma unroll
      for (int cc = 0; cc < 8; ++cc){
        float az = 0.f, ar_ = 0.f;
        #pragma unroll
        for (int i = 0; i < 8; ++i){ az += hd[i]*uz[cc][i]; ar_ += hd[i]*ur[cc][i]; }
        accz[cc] = az; accr[cc] = ar_;
      }
      #pragma unroll
      for (int cc = 0; cc < 8; ++cc){
        float v = accz[cc];
        #pragma unroll
        for (int o = 32; o; o >>= 1) v += __shfl_down(v, o);
        if (lane == 0) redA[wv][cc] = v;
        v = accr[cc];
        #pragma unroll
        for (int o = 32; o; o >>= 1) v += __shfl_down(v, o);
        if (lane == 0) redB[wv][cc] = v;
      }
      __syncthreads();
      float zreg = 0.f;
      if (t < 8){
        float s = redA[0][t]+redA[1][t]+redA[2][t]+redA[3][t] + pz;
        zreg = 1.f/(1.f + expf(-s));                 // register, used in phase B
      } else if (t < 16){
        int cc = t - 8;
        float s = redB[0][cc]+redB[1][cc]+redB[2][cc]+redB[3][cc] + pr;
        float r = 1.f/(1.f + expf(-s));
        pubTag(rhdP + cc*256 + w, e + 1, r * ldsHd[cc]);  // rhd payload
      }
      __syncthreads();                               // drain rhd exchs (vmcnt)
      if (t == 0) pubMark(mark + w, e + 1);          // marker: rhd(e+1) committed

      // ---------- phase B: htil = tanh(pre_h + (r*hd)@U2); h update ----------
      int okB = pollMark(mark + t, e + 1);
      u64 rw[8];
      int okQ = okB ? loadPay8(rhdP, t, e + 1, rw) : 0;
      if (__syncthreads_or(!okQ)) goto bail;
      float rv[8];
      #pragma unroll
      for (int i = 0; i < 8; ++i) rv[i] = lo32f(rw[i]);

      float acch[8];
      #pragma unroll
      for (int cc = 0; cc < 8; ++cc){
        float a = 0.f;
        #pragma unroll
        for (int i = 0; i < 8; ++i) a += rv[i]*uh[cc][i];
        acch[cc] = a;
      }
      #pragma unroll
      for (int cc = 0; cc < 8; ++cc){
        float v = acch[cc];
        #pragma unroll
        for (int o = 32; o; o >>= 1) v += __shfl_down(v, o);
        if (lane == 0) redH[wv][cc] = v;
      }
      __syncthreads();
      if (t < 8){
        float u2   = redH[0][t]+redH[1][t]+redH[2][t]+redH[3][t] + ph;
        float htil = tanhf(u2);
        float z = zreg, hdv = ldsHd[t], hold = ldsH[t];
        float hp = z*hdv + (1.f - z)*htil;
        float dh = (1.f - z)*(htil - hdv);
        pubTag(hP + t*256 + w, e + 2, hold + dtv*dh);      // h payload
        if (g == 4095) pubTag(hpP + t*256 + w, e + 2, hp); // hp for the mid-MLP
        if (g >= 4096) HpDec[(size_t)(8190 - g)*2048 + 8*w + t] = hp; // pre-reversed
      }
      __syncthreads();                               // drain h exchs (vmcnt)
      if (t == 0) pubMark(mark + w, e + 2);          // marker: h(e+2) committed
      e += 2;
    }
  }
  return;

bail:
  if (t == 0) HpDec[w] = 77777.f;    // loud, diagnosable failure signature
}

// ---------------- launch ----------------
extern "C" void kernel_launch(void* const* d_in, const int* in_sizes, int n_in,
                              void* d_out, int out_size, void* d_ws, size_t ws_size,
                              hipStream_t stream){
  (void)in_sizes; (void)n_in;
  const float* seq   = (const float*)d_in[0];
  const float* mask  = (const float*)d_in[1];
  const float* delta = (const float*)d_in[2];
  const float* dt    = (const float*)d_in[3];
  const float* h0    = (const float*)d_in[4];
  /* d_in[5] = dh0: carried dh never read by the reference cell */
  const float* prex0 = (const float*)d_in[6];
  const float* Wgx   = (const float*)d_in[7];
  const float* bgx   = (const float*)d_in[8];
  const float* Wgh   = (const float*)d_in[9];
  const float* bgh   = (const float*)d_in[10];
  const float* W     = (const float*)d_in[11];
  const float* U     = (const float*)d_in[12];
  const float* V     = (const float*)d_in[13];
  const float* b     = (const float*)d_in[14];
  const float* We    = (const float*)d_in[15];
  const float* be    = (const float*)d_in[16];
  const float* Wd    = (const float*)d_in[17];
  const float* bd    = (const float*)d_in[18];
  const float* Wo    = (const float*)d_in[19];
  const float* bo    = (const float*)d_in[20];

  float* wsf = (float*)d_ws;
  size_t wsFloats = ws_size / 4;
  size_t off = 0;
  u64*   pub    = (u64*)(wsf + off);  off += 13312;      // 6656 u64 (planes+feat+mark)
  int*   ctrl   = (int*)(wsf + off);  off += 1024;       // arrival counters
  float* meanv  = wsf + off;  off += 512;
  float* Sp     = wsf + off;  off += (size_t)64*512;
  float* Cp     = wsf + off;  off += (size_t)64*512;
  float* Gh     = wsf + off;  off += (size_t)4096*2048;
  float* xh_all = wsf + off;  off += (size_t)NSTEP*512;
  float* HpDec  = wsf + off;  off += (size_t)4095*2048;
  size_t fixedF = off;

  // chunk area: overlays {Gx, scan temps} during precompute, PreTab chunk after
  float* area  = wsf + fixedF;
  float* Gx    = area;                                   // 4096*512
  float* segA  = area + (size_t)4096*512;                // 64*512
  float* segC  = segA + (size_t)64*512;
  float* segX0 = segC + (size_t)64*512;
  size_t preNeed = (size_t)4096*512 + (size_t)3*64*512;

  size_t areaF = (wsFloats > fixedF) ? (wsFloats - fixedF) : 0;
  long chunkSteps = (long)(areaF / 6144);
  if (areaF < preNeed || chunkSteps < 64){
    fillK<<<dim3(256), dim3(256), 0, stream>>>((float*)d_out, out_size,
                                               1.0e6f + (float)(ws_size >> 20));
    return;
  }
  if (chunkSteps > NSTEP) chunkSteps = NSTEP;
  int nch  = (int)((NSTEP + chunkSteps - 1) / chunkSteps);
  if (nch > 128) nch = 128;                        // ctrl capacity guard
  int clen = (NSTEP + nch - 1) / nch;

  // ---- precompute ----
  mean1K<<<dim3(64), dim3(512), 0, stream>>>(seq, mask, Sp, Cp);
  mean2K<<<dim3(1),  dim3(512), 0, stream>>>(Sp, Cp, meanv);
  gemmK<<<dim3(4, 32),  dim3(256), 0, stream>>>(delta, Wgx, Gx, 4096, 512, 512, bgx, 1, 0, 0, 0);
  gemmK<<<dim3(16, 32), dim3(256), 0, stream>>>(delta, Wgh, Gh, 4096, 2048, 512, bgh, 1, 0, 0, 0);
  scanSegK<<<dim3(64), dim3(512), 0, stream>>>(Gx, mask, seq, meanv, segA, segC);
  scanFixK<<<dim3(1),  dim3(512), 0, stream>>>(segA, segC, prex0, segX0);
  scanEmitK<<<dim3(64), dim3(512), 0, stream>>>(Gx, mask, seq, meanv, segX0, xh_all);
  initK<<<dim3(1), dim3(256), 0, stream>>>(pub, ctrl, h0);

  // ---- chunked recurrence: [PreTab GEMMs] then persistent marker-dataflow ----
  int ev = 0, chunkIdx = 0;
  for (int c0 = 0; c0 < NSTEP; c0 += clen, ++chunkIdx){
    int len = (c0 + clen <= NSTEP) ? clen : (NSTEP - c0);
    int gy  = (len + 127) / 128;
    gemmK<<<dim3(48, gy), dim3(256), 0, stream>>>(xh_all + (size_t)c0*512, W, area,
                                                  len, 6144, 512, b, 0, 0, 0, 0);
    gemmK<<<dim3(48, gy), dim3(256), 0, stream>>>(mask, V, area,
                                                  len, 6144, 512, nullptr, 0, 1, 1, c0);

    rnnPersK<<<dim3(256), dim3(256), 0, stream>>>(U, area, c0, len, ev, Gh, dt,
                                                  We, be, Wd, bd,
                                                  pub, HpDec, ctrl + 4*chunkIdx);
    ev += 2*len + ((c0 <= 4096 && 4096 < c0 + len) ? 2 : 0);
  }

  // out = HpDec @ Wo + bo : 4095x512, K=2048 (HpDec stored pre-reversed)
  gemmK<<<dim3(4, 32), dim3(256), 0, stream>>>(HpDec, Wo, (float*)d_out,
                                               4095, 512, 2048, bo, 0, 0, 0, 0);
}